// Round 3
// baseline (1779.075 us; speedup 1.0000x reference)
//
#include <hip/hip_runtime.h>
#include <stdint.h>

#define NN 100000     // nodes
#define NE 1600000    // edges
#define NB 256        // graphs
#define DIN 128
#define HH 256
#define BN_EPS 1e-5f

typedef unsigned short bf16_t;
typedef __attribute__((ext_vector_type(8))) short short8;
typedef __attribute__((ext_vector_type(4))) short short4v;
typedef __attribute__((ext_vector_type(4))) float f32x4;

__device__ __forceinline__ float bf2f(unsigned short u) {
    union { unsigned int i; float f; } v;
    v.i = ((unsigned int)u) << 16;
    return v.f;
}
__device__ __forceinline__ bf16_t f2bf(float f) {
    union { float f; unsigned int i; } v;
    v.f = f;
    unsigned int x = v.i;
    return (bf16_t)((x + 0x7fffu + ((x >> 16) & 1u)) >> 16);
}
// dual-dtype param read: flag=1 -> fp32 storage, flag=0 -> bf16 storage
__device__ __forceinline__ float ldp(const void* b, int i, int f) {
    return f ? ((const float*)b)[i] : bf2f(((const unsigned short*)b)[i]);
}

// ---------------- dtype detection ----------------
// If float inputs are fp32, reading x as bf16 halves yields uniform-random
// exponent fields -> some |v|>1e6 among 128 samples (p ~ 1-1e-40).
// Confirmation: rv1 (all ones): fp32 word 0x3F800000 has low16==0.
__global__ __launch_bounds__(64) void detect_kernel(const void* xraw, const void* rvraw,
                                                    int* __restrict__ flag) {
    int lane = threadIdx.x;
    const unsigned short* xs = (const unsigned short*)xraw;
    float v0 = bf2f(xs[lane * 2]);
    float v1 = bf2f(xs[lane * 2 + 1]);
    bool crazy = !(fabsf(v0) < 1e6f) || !(fabsf(v1) < 1e6f);  // catches NaN too
    unsigned long long m = __ballot(crazy);
    if (lane == 0) {
        unsigned int rw = ((const unsigned int*)rvraw)[0];
        int isf32 = (m != 0ull) || ((rw & 0xffffu) == 0u);
        *flag = isf32 ? 1 : 0;
    }
}

// ---------------- canonicalization ----------------
__global__ __launch_bounds__(256) void conv_to_bf16(const void* __restrict__ src,
                                                    bf16_t* __restrict__ dst, int n,
                                                    const int* __restrict__ flag) {
    int i = blockIdx.x * blockDim.x + threadIdx.x;
    int f = *flag;
    if (i < n) dst[i] = f ? f2bf(((const float*)src)[i]) : ((const bf16_t*)src)[i];
}
__global__ __launch_bounds__(256) void conv_to_f32(const void* __restrict__ src,
                                                   float* __restrict__ dst, int n,
                                                   const int* __restrict__ flag) {
    int i = blockIdx.x * blockDim.x + threadIdx.x;
    int f = *flag;
    if (i < n) dst[i] = f ? ((const float*)src)[i] : bf2f(((const bf16_t*)src)[i]);
}

// ---------------- CSR build ----------------
__global__ __launch_bounds__(256) void hist_kernel(const int* __restrict__ dst,
                                                   const float* __restrict__ ew,
                                                   int* __restrict__ count,
                                                   float* __restrict__ degw) {
    int i = blockIdx.x * blockDim.x + threadIdx.x;
    if (i < NE) {
        int d = dst[i];
        atomicAdd(&count[d], 1);
        atomicAdd(&degw[d], ew[i]);
    }
}

__global__ __launch_bounds__(256) void dinv_kernel(const float* __restrict__ degw,
                                                   float* __restrict__ dinv) {
    int i = blockIdx.x * blockDim.x + threadIdx.x;
    if (i < NN) dinv[i] = rsqrtf(degw[i] + 1.0f);  // + self-loop weight 1 -> always >= 1
}

__global__ __launch_bounds__(1024) void scan_rowptr(const int* __restrict__ count,
                                                    int* __restrict__ rowptr, int n) {
    __shared__ int sd[1024];
    __shared__ int s_run;
    int tid = threadIdx.x;
    if (tid == 0) s_run = 0;
    __syncthreads();
    for (int base = 0; base < n; base += 4096) {
        int i0 = base + tid * 4;
        int v[4];
        int tsum = 0;
#pragma unroll
        for (int k = 0; k < 4; k++) {
            v[k] = (i0 + k < n) ? count[i0 + k] : 0;
            tsum += v[k];
        }
        sd[tid] = tsum;
        __syncthreads();
        for (int off = 1; off < 1024; off <<= 1) {
            int t = (tid >= off) ? sd[tid - off] : 0;
            __syncthreads();
            sd[tid] += t;
            __syncthreads();
        }
        int excl = s_run + sd[tid] - tsum;
        __syncthreads();
        if (tid == 1023) s_run += sd[1023];
#pragma unroll
        for (int k = 0; k < 4; k++) {
            if (i0 + k < n) rowptr[i0 + k] = excl;
            excl += v[k];
        }
        __syncthreads();
    }
    if (tid == 0) rowptr[n] = s_run;
}

__global__ __launch_bounds__(256) void scatter_kernel(const int* __restrict__ src,
                                                      const int* __restrict__ dst,
                                                      const float* __restrict__ ew,
                                                      const float* __restrict__ dinv,
                                                      const int* __restrict__ rowptr,
                                                      int* __restrict__ fill,
                                                      int* __restrict__ ccol,
                                                      float* __restrict__ cval) {
    int i = blockIdx.x * blockDim.x + threadIdx.x;
    if (i < NE) {
        int s = src[i], d = dst[i];
        float nv = dinv[s] * ew[i] * dinv[d];
        int pos = rowptr[d] + atomicAdd(&fill[d], 1);
        ccol[pos] = s;
        cval[pos] = nv;
    }
}

__global__ __launch_bounds__(256) void ghist_kernel(const int* __restrict__ batch, int* __restrict__ gcount) {
    int i = blockIdx.x * blockDim.x + threadIdx.x;
    if (i < NN) atomicAdd(&gcount[batch[i]], 1);
}

// ---------------- W pre-pack into MFMA B-fragment order (dual-dtype read) ----------------
// P[((t*S+s)*64+lane)*8+j] = W[(32s + 8*(lane>>4) + j)*256 + t*16 + (lane&15)]
__global__ __launch_bounds__(256) void pack_w(const void* __restrict__ W, bf16_t* __restrict__ P,
                                              int S, const int* __restrict__ flag) {
    int idx = blockIdx.x * blockDim.x + threadIdx.x;
    if (idx >= 16 * S * 64) return;
    int f = *flag;
    int lane = idx & 63;
    int ts = idx >> 6;
    int s = ts % S;
    int t = ts / S;
    int q = lane >> 4, m = lane & 15;
    int colbase = t * 16 + m;
    int krow = 32 * s + 8 * q;
#pragma unroll
    for (int j = 0; j < 8; j++) P[idx * 8 + j] = f2bf(ldp(W, (krow + j) * 256 + colbase, f));
}

// ---------------- fused layer: aggregate -> MFMA -> BN/ReLU -> pool ----------------
template <int K, bool WRITE_OUT>
__global__ __launch_bounds__(256) void fused_layer(const bf16_t* __restrict__ X,
                                                   const bf16_t* __restrict__ P,
                                                   const int* __restrict__ rowptr,
                                                   const int* __restrict__ ccol,
                                                   const float* __restrict__ cval,
                                                   const float* __restrict__ dinv,
                                                   const int* __restrict__ batch,
                                                   const void* __restrict__ bias,
                                                   const void* __restrict__ gam,
                                                   const void* __restrict__ bet,
                                                   const void* __restrict__ rmean,
                                                   const void* __restrict__ rvar,
                                                   const int* __restrict__ flag,
                                                   bf16_t* __restrict__ outbuf,
                                                   float* __restrict__ embf) {
    constexpr int S = K / 32;
    constexpr int ROWELL = K + 8;
    constexpr int F = K / 64;
    __shared__ __align__(16) bf16_t tile[4][16 * ROWELL];
    int fl = *flag;
    int widx = threadIdx.x >> 6;
    int lane = threadIdx.x & 63;
    int gwave = blockIdx.x * 4 + widx;
    bool active = (gwave * 16) < NN;
    int rowbase = active ? gwave * 16 : 0;
    bf16_t* T = tile[widx];
    int f0 = lane * F;

    // phase 1: aggregate 16 nodes into LDS A-tile (fp32 accumulate, bf16 store)
    for (int r = 0; r < 16; r++) {
        int node = rowbase + r;
        float di = dinv[node];
        float selfw = di * di;
        float acc[F];
        if constexpr (K == 128) {
            uint32_t w = *(const uint32_t*)(X + (size_t)node * K + f0);
            acc[0] = bf2f((unsigned short)(w & 0xffffu)) * selfw;
            acc[1] = bf2f((unsigned short)(w >> 16)) * selfw;
        } else {
            short4v h = *(const short4v*)(X + (size_t)node * K + f0);
#pragma unroll
            for (int j = 0; j < 4; j++) acc[j] = bf2f((unsigned short)h[j]) * selfw;
        }
        int e0 = rowptr[node], e1 = rowptr[node + 1];
        for (int e = e0; e < e1; e++) {
            int c = ccol[e];
            float v = cval[e];
            if constexpr (K == 128) {
                uint32_t w = *(const uint32_t*)(X + (size_t)c * K + f0);
                acc[0] += bf2f((unsigned short)(w & 0xffffu)) * v;
                acc[1] += bf2f((unsigned short)(w >> 16)) * v;
            } else {
                short4v h = *(const short4v*)(X + (size_t)c * K + f0);
#pragma unroll
                for (int j = 0; j < 4; j++) acc[j] += bf2f((unsigned short)h[j]) * v;
            }
        }
        if constexpr (K == 128) {
            uint32_t w = (uint32_t)f2bf(acc[0]) | ((uint32_t)f2bf(acc[1]) << 16);
            *(uint32_t*)&T[r * ROWELL + f0] = w;
        } else {
            short4v o;
#pragma unroll
            for (int j = 0; j < 4; j++) o[j] = (short)f2bf(acc[j]);
            *(short4v*)&T[r * ROWELL + f0] = o;
        }
    }
    __syncthreads();

    // phase 2: 16x16x32 bf16 MFMA over the LDS tile
    int m = lane & 15, q = lane >> 4;
    f32x4 acc16[16];
#pragma unroll
    for (int t = 0; t < 16; t++) acc16[t] = (f32x4){0.f, 0.f, 0.f, 0.f};
#pragma unroll
    for (int s = 0; s < S; s++) {
        short8 af = *(const short8*)&T[m * ROWELL + 32 * s + 8 * q];
#pragma unroll
        for (int t = 0; t < 16; t++) {
            short8 bfr = *(const short8*)(P + ((size_t)(t * S + s) * 64 + lane) * 8);
            acc16[t] = __builtin_amdgcn_mfma_f32_16x16x32_bf16(af, bfr, acc16[t], 0, 0, 0);
        }
    }

    // epilogue: bias+BN+ReLU, optional feature write, pooled atomics
    int g0 = batch[rowbase];
    int g15 = batch[rowbase + 15];
    bool uni = (g0 == g15);
#pragma unroll
    for (int t = 0; t < 16; t++) {
        int col = t * 16 + m;
        float a = rsqrtf(ldp(rvar, col, fl) + BN_EPS) * ldp(gam, col, fl);
        float bc = (ldp(bias, col, fl) - ldp(rmean, col, fl)) * a + ldp(bet, col, fl);
        float colsum = 0.f;
#pragma unroll
        for (int r = 0; r < 4; r++) {
            int row = q * 4 + r;
            float v = fmaxf(acc16[t][r] * a + bc, 0.f);
            if (WRITE_OUT && active) outbuf[(size_t)(rowbase + row) * 256 + col] = f2bf(v);
            if (uni) {
                colsum += v;
            } else if (active) {
                atomicAdd(&embf[(size_t)batch[rowbase + row] * 256 + col], v);
            }
        }
        if (uni) {
            colsum += __shfl_xor(colsum, 16, 64);
            colsum += __shfl_xor(colsum, 32, 64);
            if (q == 0 && active) atomicAdd(&embf[(size_t)g0 * 256 + col], colsum);
        }
    }
}

// ---------------- classifier MLP + emb finalize (one block per graph) ----------------
__global__ __launch_bounds__(256) void classifier_kernel(const float* __restrict__ embf,
                                                         const int* __restrict__ gcount,
                                                         const void* cW1, const void* cb1,
                                                         const void* cg1, const void* cbe1,
                                                         const void* crm1, const void* crv1,
                                                         const void* cW2, const void* cb2,
                                                         const void* cg2, const void* cbe2,
                                                         const void* crm2, const void* crv2,
                                                         const void* cW3, const void* cb3,
                                                         const int* __restrict__ flag,
                                                         void* __restrict__ d_out) {
    int b = blockIdx.x, tid = threadIdx.x;
    int fl = *flag;
    __shared__ float se[256];
    __shared__ float z1[256];
    __shared__ float z2[128];
    float cnt = (float)gcount[b];
    float mval = embf[b * 256 + tid] / fmaxf(cnt, 1.f);
    se[tid] = mval;
    if (fl) ((float*)d_out)[512 + b * 256 + tid] = mval;
    else    ((bf16_t*)d_out)[512 + b * 256 + tid] = f2bf(mval);
    __syncthreads();
    {
        float s = 0.f;
        for (int k = 0; k < 256; k++) s += se[k] * ldp(cW1, k * 256 + tid, fl);
        s += ldp(cb1, tid, fl);
        s = (s - ldp(crm1, tid, fl)) * rsqrtf(ldp(crv1, tid, fl) + BN_EPS) * ldp(cg1, tid, fl) + ldp(cbe1, tid, fl);
        z1[tid] = fmaxf(s, 0.f);
    }
    __syncthreads();
    if (tid < 128) {
        float s = 0.f;
        for (int k = 0; k < 256; k++) s += z1[k] * ldp(cW2, k * 128 + tid, fl);
        s += ldp(cb2, tid, fl);
        s = (s - ldp(crm2, tid, fl)) * rsqrtf(ldp(crv2, tid, fl) + BN_EPS) * ldp(cg2, tid, fl) + ldp(cbe2, tid, fl);
        z2[tid] = fmaxf(s, 0.f);
    }
    __syncthreads();
    if (tid < 2) {
        float s = 0.f;
        for (int k = 0; k < 128; k++) s += z2[k] * ldp(cW3, k * 2 + tid, fl);
        s += ldp(cb3, tid, fl);
        if (fl) ((float*)d_out)[b * 2 + tid] = s;
        else    ((bf16_t*)d_out)[b * 2 + tid] = f2bf(s);
    }
}

// ---------------- launch ----------------
extern "C" void kernel_launch(void* const* d_in, const int* in_sizes, int n_in,
                              void* d_out, int out_size, void* d_ws, size_t ws_size,
                              hipStream_t stream) {
    const void* x    = d_in[0];
    const int*  eidx = (const int*)d_in[1];
    const void* ew   = d_in[2];
    const int*  batch= (const int*)d_in[3];
    const void* W1   = d_in[4];
    const void* b1   = d_in[5];
    const void* g1   = d_in[6];
    const void* be1  = d_in[7];
    const void* rm1  = d_in[8];
    const void* rv1  = d_in[9];
    const void* W2   = d_in[10];
    const void* b2   = d_in[11];
    const void* g2   = d_in[12];
    const void* be2  = d_in[13];
    const void* rm2  = d_in[14];
    const void* rv2  = d_in[15];
    const void* cW1  = d_in[16];
    const void* cb1  = d_in[17];
    const void* cg1  = d_in[18];
    const void* cbe1 = d_in[19];
    const void* crm1 = d_in[20];
    const void* crv1 = d_in[21];
    const void* cW2  = d_in[22];
    const void* cb2  = d_in[23];
    const void* cg2  = d_in[24];
    const void* cbe2 = d_in[25];
    const void* crm2 = d_in[26];
    const void* crv2 = d_in[27];
    const void* cW3  = d_in[28];
    const void* cb3  = d_in[29];

    const int* src = eidx;
    const int* dst = eidx + NE;

    char* p = (char*)d_ws;
    auto alloc = [&](size_t bytes) -> void* {
        void* r = (void*)p;
        p += (bytes + 255) & ~(size_t)255;
        return r;
    };
    int*    dflag  = (int*)alloc(256);
    float*  degw   = (float*)alloc((size_t)NN * 4);
    float*  dinv   = (float*)alloc((size_t)NN * 4);
    int*    count  = (int*)alloc((size_t)NN * 4);
    int*    fill   = (int*)alloc((size_t)NN * 4);
    int*    rowptr = (int*)alloc((size_t)(NN + 1) * 4);
    int*    ccol   = (int*)alloc((size_t)NE * 4);
    float*  cval   = (float*)alloc((size_t)NE * 4);
    float*  ewc    = (float*)alloc((size_t)NE * 4);       // canonical fp32 edge weights
    bf16_t* xc     = (bf16_t*)alloc((size_t)NN * DIN * 2); // canonical bf16 x
    bf16_t* pW1    = (bf16_t*)alloc((size_t)DIN * 256 * 2);
    bf16_t* pW2    = (bf16_t*)alloc((size_t)256 * 256 * 2);
    bf16_t* hl1    = (bf16_t*)alloc((size_t)NN * 256 * 2);
    int*    gcount = (int*)alloc((size_t)NB * 4);
    float*  embf   = (float*)alloc((size_t)NB * 256 * 4);
    // total ~ 98 MB

    hipMemsetAsync(degw, 0, (size_t)NN * 4, stream);
    hipMemsetAsync(count, 0, (size_t)NN * 4, stream);
    hipMemsetAsync(fill, 0, (size_t)NN * 4, stream);
    hipMemsetAsync(gcount, 0, (size_t)NB * 4, stream);
    hipMemsetAsync(embf, 0, (size_t)NB * 256 * 4, stream);

    detect_kernel<<<1, 64, 0, stream>>>(x, rv1, dflag);
    conv_to_bf16<<<(NN * DIN + 255) / 256, 256, 0, stream>>>(x, xc, NN * DIN, dflag);
    conv_to_f32<<<(NE + 255) / 256, 256, 0, stream>>>(ew, ewc, NE, dflag);

    hist_kernel<<<NE / 256, 256, 0, stream>>>(dst, ewc, count, degw);
    dinv_kernel<<<(NN + 255) / 256, 256, 0, stream>>>(degw, dinv);
    scan_rowptr<<<1, 1024, 0, stream>>>(count, rowptr, NN);
    scatter_kernel<<<NE / 256, 256, 0, stream>>>(src, dst, ewc, dinv, rowptr, fill, ccol, cval);
    ghist_kernel<<<(NN + 255) / 256, 256, 0, stream>>>(batch, gcount);

    pack_w<<<16, 256, 0, stream>>>(W1, pW1, DIN / 32, dflag);
    pack_w<<<32, 256, 0, stream>>>(W2, pW2, 256 / 32, dflag);

    int nwaves = NN / 16;                    // 6250
    int blocks = (nwaves + 3) / 4;           // 1563
    fused_layer<128, true><<<blocks, 256, 0, stream>>>(xc, pW1, rowptr, ccol, cval, dinv, batch,
                                                       b1, g1, be1, rm1, rv1, dflag, hl1, embf);
    fused_layer<256, false><<<blocks, 256, 0, stream>>>(hl1, pW2, rowptr, ccol, cval, dinv, batch,
                                                        b2, g2, be2, rm2, rv2, dflag, nullptr, embf);

    classifier_kernel<<<NB, 256, 0, stream>>>(embf, gcount,
                                              cW1, cb1, cg1, cbe1, crm1, crv1,
                                              cW2, cb2, cg2, cbe2, crm2, crv2,
                                              cW3, cb3, dflag, d_out);
}

// Round 4
// 1015.090 us; speedup vs baseline: 1.7526x; 1.7526x over previous
//
#include <hip/hip_runtime.h>
#include <stdint.h>

#define NN 100000     // nodes
#define NE 1600000    // edges
#define NB 256        // graphs
#define DIN 128
#define HH 256
#define BN_EPS 1e-5f

typedef unsigned short bf16_t;
typedef __attribute__((ext_vector_type(8))) short short8;
typedef __attribute__((ext_vector_type(4))) short short4v;
typedef __attribute__((ext_vector_type(4))) float f32x4;

struct __align__(8) EPair { int c; float v; };

__device__ __forceinline__ float bf2f(unsigned short u) {
    union { unsigned int i; float f; } v;
    v.i = ((unsigned int)u) << 16;
    return v.f;
}
__device__ __forceinline__ bf16_t f2bf(float f) {
    union { float f; unsigned int i; } v;
    v.f = f;
    unsigned int x = v.i;
    return (bf16_t)((x + 0x7fffu + ((x >> 16) & 1u)) >> 16);
}
// dual-dtype param read: flag=1 -> fp32 storage, flag=0 -> bf16 storage
__device__ __forceinline__ float ldp(const void* b, int i, int f) {
    return f ? ((const float*)b)[i] : bf2f(((const unsigned short*)b)[i]);
}

// ---------------- dtype detection ----------------
__global__ __launch_bounds__(64) void detect_kernel(const void* xraw, const void* rvraw,
                                                    int* __restrict__ flag) {
    int lane = threadIdx.x;
    const unsigned short* xs = (const unsigned short*)xraw;
    float v0 = bf2f(xs[lane * 2]);
    float v1 = bf2f(xs[lane * 2 + 1]);
    bool crazy = !(fabsf(v0) < 1e6f) || !(fabsf(v1) < 1e6f);
    unsigned long long m = __ballot(crazy);
    if (lane == 0) {
        unsigned int rw = ((const unsigned int*)rvraw)[0];
        int isf32 = (m != 0ull) || ((rw & 0xffffu) == 0u);
        *flag = isf32 ? 1 : 0;
    }
}

// ---------------- merged preprocessing ----------------
// A: canonicalize x -> bf16;  B: canonicalize ew -> fp32 + dst histogram (+weighted degree);
// C: graph histogram with wave-run aggregation (batch is sorted).
__global__ __launch_bounds__(256) void prep_kernel(const void* __restrict__ x, bf16_t* __restrict__ xc,
                                                   const void* __restrict__ ew, float* __restrict__ ewc,
                                                   const int* __restrict__ dst,
                                                   const int* __restrict__ batch,
                                                   int* __restrict__ count, float* __restrict__ degw,
                                                   int* __restrict__ gcount,
                                                   const int* __restrict__ flag) {
    int i = blockIdx.x * blockDim.x + threadIdx.x;
    int stride = gridDim.x * blockDim.x;
    int f = *flag;
    for (int j = i; j < NN * DIN; j += stride)
        xc[j] = f ? f2bf(((const float*)x)[j]) : ((const bf16_t*)x)[j];
    for (int j = i; j < NE; j += stride) {
        float w = f ? ((const float*)ew)[j] : bf2f(((const bf16_t*)ew)[j]);
        ewc[j] = w;
        int d = dst[j];
        atomicAdd(&count[d], 1);
        atomicAdd(&degw[d], w);
    }
    int lane = threadIdx.x & 63;
    for (int j = i; j < NN; j += stride) {
        int b = batch[j];
        bool boundary = (lane == 0) || (j == 0) || (batch[j - 1] != b);
        unsigned long long bmask = __ballot(boundary);
        bool islast = (lane == 63) || (j + 1 >= NN) || (batch[j + 1] != b);
        if (islast) {
            unsigned long long below = bmask & ((lane == 63) ? ~0ull : ((1ull << (lane + 1)) - 1ull));
            int first = 63 - __builtin_clzll(below);
            atomicAdd(&gcount[b], lane - first + 1);
        }
    }
}

// ---------------- exclusive scan of count -> rowptr (single block, shfl-based) ----------------
__global__ __launch_bounds__(1024) void scan_rowptr(const int* __restrict__ count,
                                                    int* __restrict__ rowptr, int n) {
    __shared__ int wsum[16];
    __shared__ int s_tot;
    __shared__ int s_run;
    int tid = threadIdx.x, lane = tid & 63, wid = tid >> 6;
    if (tid == 0) s_run = 0;
    __syncthreads();
    for (int base = 0; base < n; base += 4096) {
        int i0 = base + tid * 4;
        int v[4];
        int tsum = 0;
#pragma unroll
        for (int k = 0; k < 4; k++) {
            v[k] = (i0 + k < n) ? count[i0 + k] : 0;
            tsum += v[k];
        }
        int sc = tsum;
#pragma unroll
        for (int off = 1; off < 64; off <<= 1) {
            int t = __shfl_up(sc, off, 64);
            if (lane >= off) sc += t;
        }
        if (lane == 63) wsum[wid] = sc;
        __syncthreads();
        if (wid == 0 && lane < 16) {
            int ws = wsum[lane];
            int scw = ws;
#pragma unroll
            for (int off = 1; off < 16; off <<= 1) {
                int t = __shfl_up(scw, off, 64);
                if (lane >= off) scw += t;
            }
            if (lane == 15) s_tot = scw;
            wsum[lane] = scw - ws;
        }
        __syncthreads();
        int excl = s_run + wsum[wid] + (sc - tsum);
#pragma unroll
        for (int k = 0; k < 4; k++) {
            if (i0 + k < n) rowptr[i0 + k] = excl;
            excl += v[k];
        }
        __syncthreads();
        if (tid == 0) s_run += s_tot;
    }
    if (tid == 0) rowptr[n] = s_run;
}

// ---------------- scatter edges into CSR (8B interleaved pairs, back-fill via count) ----------------
__global__ __launch_bounds__(256) void scatter_kernel(const int* __restrict__ src,
                                                      const int* __restrict__ dst,
                                                      const float* __restrict__ ewc,
                                                      const float* __restrict__ degw,
                                                      const int* __restrict__ rowptr,
                                                      int* __restrict__ count,
                                                      EPair* __restrict__ ep) {
    int i = blockIdx.x * blockDim.x + threadIdx.x;
    if (i < NE) {
        int s = src[i], d = dst[i];
        float nv = rsqrtf(degw[s] + 1.0f) * ewc[i] * rsqrtf(degw[d] + 1.0f);
        int pos = rowptr[d] + atomicSub(&count[d], 1) - 1;
        EPair pr;
        pr.c = s;
        pr.v = nv;
        ep[pos] = pr;
    }
}

// ---------------- W pre-pack into MFMA B-fragment order (both weights, one launch) ----------------
__device__ __forceinline__ void pack_one(const void* __restrict__ W, bf16_t* __restrict__ P,
                                         int S, int idx, int f) {
    int lane = idx & 63;
    int ts = idx >> 6;
    int s = ts % S;
    int t = ts / S;
    int q = lane >> 4, m = lane & 15;
    int colbase = t * 16 + m;
    int krow = 32 * s + 8 * q;
#pragma unroll
    for (int j = 0; j < 8; j++) P[idx * 8 + j] = f2bf(ldp(W, (krow + j) * 256 + colbase, f));
}

__global__ __launch_bounds__(256) void pack_both(const void* __restrict__ W1, bf16_t* __restrict__ P1,
                                                 const void* __restrict__ W2, bf16_t* __restrict__ P2,
                                                 const int* __restrict__ flag) {
    int idx = blockIdx.x * blockDim.x + threadIdx.x;
    int f = *flag;
    if (idx < 16 * 4 * 64) {
        pack_one(W1, P1, 4, idx, f);
    } else {
        idx -= 16 * 4 * 64;
        if (idx < 16 * 8 * 64) pack_one(W2, P2, 8, idx, f);
    }
}

// ---------------- fused layer: batched gather/aggregate -> MFMA -> BN/ReLU -> pool ----------------
template <int K, bool WRITE_OUT>
__global__ __launch_bounds__(256) void fused_layer(const bf16_t* __restrict__ X,
                                                   const bf16_t* __restrict__ P,
                                                   const int* __restrict__ rowptr,
                                                   const EPair* __restrict__ ep,
                                                   const float* __restrict__ degw,
                                                   const int* __restrict__ batch,
                                                   const void* __restrict__ bias,
                                                   const void* __restrict__ gam,
                                                   const void* __restrict__ bet,
                                                   const void* __restrict__ rmean,
                                                   const void* __restrict__ rvar,
                                                   const int* __restrict__ flag,
                                                   bf16_t* __restrict__ outbuf,
                                                   float* __restrict__ embf) {
    constexpr int S = K / 32;
    constexpr int ROWELL = K + 8;
    constexpr int F = K / 64;                 // 2 (K=128) or 4 (K=256) features/lane
    constexpr int UN = (K == 128) ? 8 : 6;    // gather batch width (MLP)
    __shared__ __align__(16) bf16_t tile[4][16 * ROWELL];
    int fl = *flag;
    int widx = threadIdx.x >> 6;
    int lane = threadIdx.x & 63;
    int gwave = blockIdx.x * 4 + widx;
    bool active = (gwave * 16) < NN;
    int rowbase = active ? gwave * 16 : 0;
    bf16_t* T = tile[widx];
    int f0 = lane * F;

    // phase 1: aggregate 16 nodes into the LDS A-tile, UN independent gathers in flight
    for (int r = 0; r < 16; r++) {
        int node = rowbase + r;
        float acc[F];
        float di = rsqrtf(degw[node] + 1.0f);
        float selfw = di * di;
        if constexpr (K == 128) {
            uint32_t w = *(const uint32_t*)(X + (size_t)node * K + f0);
            acc[0] = bf2f((unsigned short)(w & 0xffffu)) * selfw;
            acc[1] = bf2f((unsigned short)(w >> 16)) * selfw;
        } else {
            uint2 w = *(const uint2*)(X + (size_t)node * K + f0);
            acc[0] = bf2f((unsigned short)(w.x & 0xffffu)) * selfw;
            acc[1] = bf2f((unsigned short)(w.x >> 16)) * selfw;
            acc[2] = bf2f((unsigned short)(w.y & 0xffffu)) * selfw;
            acc[3] = bf2f((unsigned short)(w.y >> 16)) * selfw;
        }
        int e0 = rowptr[node], e1 = rowptr[node + 1];
        for (int e = e0; e < e1; e += UN) {
            int cc[UN];
            float vv[UN];
#pragma unroll
            for (int u = 0; u < UN; u++) {
                int idx = e + u;
                bool ok = idx < e1;
                EPair pr = ep[ok ? idx : (e1 - 1)];
                cc[u] = pr.c;
                vv[u] = ok ? pr.v : 0.f;
            }
            if constexpr (K == 128) {
                uint32_t w[UN];
#pragma unroll
                for (int u = 0; u < UN; u++) w[u] = *(const uint32_t*)(X + (size_t)cc[u] * K + f0);
#pragma unroll
                for (int u = 0; u < UN; u++) {
                    acc[0] += bf2f((unsigned short)(w[u] & 0xffffu)) * vv[u];
                    acc[1] += bf2f((unsigned short)(w[u] >> 16)) * vv[u];
                }
            } else {
                uint2 w[UN];
#pragma unroll
                for (int u = 0; u < UN; u++) w[u] = *(const uint2*)(X + (size_t)cc[u] * K + f0);
#pragma unroll
                for (int u = 0; u < UN; u++) {
                    acc[0] += bf2f((unsigned short)(w[u].x & 0xffffu)) * vv[u];
                    acc[1] += bf2f((unsigned short)(w[u].x >> 16)) * vv[u];
                    acc[2] += bf2f((unsigned short)(w[u].y & 0xffffu)) * vv[u];
                    acc[3] += bf2f((unsigned short)(w[u].y >> 16)) * vv[u];
                }
            }
        }
        if constexpr (K == 128) {
            uint32_t w = (uint32_t)f2bf(acc[0]) | ((uint32_t)f2bf(acc[1]) << 16);
            *(uint32_t*)&T[r * ROWELL + f0] = w;
        } else {
            short4v o;
#pragma unroll
            for (int j = 0; j < 4; j++) o[j] = (short)f2bf(acc[j]);
            *(short4v*)&T[r * ROWELL + f0] = o;
        }
    }
    __syncthreads();

    // phase 2: 16x16x32 bf16 MFMA over the LDS tile
    int m = lane & 15, q = lane >> 4;
    f32x4 acc16[16];
#pragma unroll
    for (int t = 0; t < 16; t++) acc16[t] = (f32x4){0.f, 0.f, 0.f, 0.f};
#pragma unroll
    for (int s = 0; s < S; s++) {
        short8 af = *(const short8*)&T[m * ROWELL + 32 * s + 8 * q];
#pragma unroll
        for (int t = 0; t < 16; t++) {
            short8 bfr = *(const short8*)(P + ((size_t)(t * S + s) * 64 + lane) * 8);
            acc16[t] = __builtin_amdgcn_mfma_f32_16x16x32_bf16(af, bfr, acc16[t], 0, 0, 0);
        }
    }

    // epilogue: bias+BN+ReLU, optional feature write, pooled atomics
    int g0 = batch[rowbase];
    int g15 = batch[rowbase + 15];
    bool uni = (g0 == g15);
#pragma unroll
    for (int t = 0; t < 16; t++) {
        int col = t * 16 + m;
        float a = rsqrtf(ldp(rvar, col, fl) + BN_EPS) * ldp(gam, col, fl);
        float bc = (ldp(bias, col, fl) - ldp(rmean, col, fl)) * a + ldp(bet, col, fl);
        float colsum = 0.f;
#pragma unroll
        for (int r = 0; r < 4; r++) {
            int row = q * 4 + r;
            float v = fmaxf(acc16[t][r] * a + bc, 0.f);
            if (WRITE_OUT && active) outbuf[(size_t)(rowbase + row) * 256 + col] = f2bf(v);
            if (uni) {
                colsum += v;
            } else if (active) {
                atomicAdd(&embf[(size_t)batch[rowbase + row] * 256 + col], v);
            }
        }
        if (uni) {
            colsum += __shfl_xor(colsum, 16, 64);
            colsum += __shfl_xor(colsum, 32, 64);
            if (q == 0 && active) atomicAdd(&embf[(size_t)g0 * 256 + col], colsum);
        }
    }
}

// ---------------- classifier MLP + emb finalize (one block per graph) ----------------
__global__ __launch_bounds__(256) void classifier_kernel(const float* __restrict__ embf,
                                                         const int* __restrict__ gcount,
                                                         const void* cW1, const void* cb1,
                                                         const void* cg1, const void* cbe1,
                                                         const void* crm1, const void* crv1,
                                                         const void* cW2, const void* cb2,
                                                         const void* cg2, const void* cbe2,
                                                         const void* crm2, const void* crv2,
                                                         const void* cW3, const void* cb3,
                                                         const int* __restrict__ flag,
                                                         void* __restrict__ d_out) {
    int b = blockIdx.x, tid = threadIdx.x;
    int fl = *flag;
    __shared__ float se[256];
    __shared__ float z1[256];
    __shared__ float z2[128];
    float cnt = (float)gcount[b];
    float mval = embf[b * 256 + tid] / fmaxf(cnt, 1.f);
    se[tid] = mval;
    if (fl) ((float*)d_out)[512 + b * 256 + tid] = mval;
    else    ((bf16_t*)d_out)[512 + b * 256 + tid] = f2bf(mval);
    __syncthreads();
    {
        float s = 0.f;
        for (int k = 0; k < 256; k++) s += se[k] * ldp(cW1, k * 256 + tid, fl);
        s += ldp(cb1, tid, fl);
        s = (s - ldp(crm1, tid, fl)) * rsqrtf(ldp(crv1, tid, fl) + BN_EPS) * ldp(cg1, tid, fl) + ldp(cbe1, tid, fl);
        z1[tid] = fmaxf(s, 0.f);
    }
    __syncthreads();
    if (tid < 128) {
        float s = 0.f;
        for (int k = 0; k < 256; k++) s += z1[k] * ldp(cW2, k * 128 + tid, fl);
        s += ldp(cb2, tid, fl);
        s = (s - ldp(crm2, tid, fl)) * rsqrtf(ldp(crv2, tid, fl) + BN_EPS) * ldp(cg2, tid, fl) + ldp(cbe2, tid, fl);
        z2[tid] = fmaxf(s, 0.f);
    }
    __syncthreads();
    if (tid < 2) {
        float s = 0.f;
        for (int k = 0; k < 128; k++) s += z2[k] * ldp(cW3, k * 2 + tid, fl);
        s += ldp(cb3, tid, fl);
        if (fl) ((float*)d_out)[b * 2 + tid] = s;
        else    ((bf16_t*)d_out)[b * 2 + tid] = f2bf(s);
    }
}

// ---------------- launch ----------------
extern "C" void kernel_launch(void* const* d_in, const int* in_sizes, int n_in,
                              void* d_out, int out_size, void* d_ws, size_t ws_size,
                              hipStream_t stream) {
    const void* x    = d_in[0];
    const int*  eidx = (const int*)d_in[1];
    const void* ew   = d_in[2];
    const int*  batch= (const int*)d_in[3];
    const void* W1   = d_in[4];
    const void* b1   = d_in[5];
    const void* g1   = d_in[6];
    const void* be1  = d_in[7];
    const void* rm1  = d_in[8];
    const void* rv1  = d_in[9];
    const void* W2   = d_in[10];
    const void* b2   = d_in[11];
    const void* g2   = d_in[12];
    const void* be2  = d_in[13];
    const void* rm2  = d_in[14];
    const void* rv2  = d_in[15];
    const void* cW1  = d_in[16];
    const void* cb1  = d_in[17];
    const void* cg1  = d_in[18];
    const void* cbe1 = d_in[19];
    const void* crm1 = d_in[20];
    const void* crv1 = d_in[21];
    const void* cW2  = d_in[22];
    const void* cb2  = d_in[23];
    const void* cg2  = d_in[24];
    const void* cbe2 = d_in[25];
    const void* crm2 = d_in[26];
    const void* crv2 = d_in[27];
    const void* cW3  = d_in[28];
    const void* cb3  = d_in[29];

    const int* src = eidx;
    const int* dst = eidx + NE;

    char* p = (char*)d_ws;
    auto alloc = [&](size_t bytes) -> void* {
        void* r = (void*)p;
        p += (bytes + 255) & ~(size_t)255;
        return r;
    };
    int*    dflag  = (int*)alloc(256);
    // --- contiguous zero-init region: degw, count, gcount, embf ---
    float*  degw   = (float*)alloc((size_t)NN * 4);
    int*    count  = (int*)alloc((size_t)NN * 4);
    int*    gcount = (int*)alloc((size_t)NB * 4);
    float*  embf   = (float*)alloc((size_t)NB * 256 * 4);
    size_t zspan = (char*)p - (char*)degw;
    // --- rest ---
    int*    rowptr = (int*)alloc((size_t)(NN + 1) * 4);
    EPair*  ep     = (EPair*)alloc((size_t)NE * 8);
    float*  ewc    = (float*)alloc((size_t)NE * 4);
    bf16_t* xc     = (bf16_t*)alloc((size_t)NN * DIN * 2);
    bf16_t* pW1    = (bf16_t*)alloc((size_t)DIN * 256 * 2);
    bf16_t* pW2    = (bf16_t*)alloc((size_t)256 * 256 * 2);
    bf16_t* hl1    = (bf16_t*)alloc((size_t)NN * 256 * 2);
    // total ~ 98 MB

    detect_kernel<<<1, 64, 0, stream>>>(x, rv1, dflag);
    hipMemsetAsync(degw, 0, zspan, stream);

    prep_kernel<<<2048, 256, 0, stream>>>(x, xc, ew, ewc, dst, batch, count, degw, gcount, dflag);
    scan_rowptr<<<1, 1024, 0, stream>>>(count, rowptr, NN);
    scatter_kernel<<<NE / 256, 256, 0, stream>>>(src, dst, ewc, degw, rowptr, count, ep);
    pack_both<<<48, 256, 0, stream>>>(W1, pW1, W2, pW2, dflag);

    int nwaves = NN / 16;                    // 6250
    int blocks = (nwaves + 3) / 4;           // 1563
    fused_layer<128, true><<<blocks, 256, 0, stream>>>(xc, pW1, rowptr, ep, degw, batch,
                                                       b1, g1, be1, rm1, rv1, dflag, hl1, embf);
    fused_layer<256, false><<<blocks, 256, 0, stream>>>(hl1, pW2, rowptr, ep, degw, batch,
                                                        b2, g2, be2, rm2, rv2, dflag, nullptr, embf);

    classifier_kernel<<<NB, 256, 0, stream>>>(embf, gcount,
                                              cW1, cb1, cg1, cbe1, crm1, crv1,
                                              cW2, cb2, cg2, cbe2, crm2, crv2,
                                              cW3, cb3, dflag, d_out);
}

// Round 5
// 933.819 us; speedup vs baseline: 1.9052x; 1.0870x over previous
//
#include <hip/hip_runtime.h>
#include <stdint.h>

#define NN 100000     // nodes
#define NE 1600000    // edges
#define NB 256        // graphs
#define DIN 128
#define HH 256
#define BN_EPS 1e-5f

typedef unsigned short bf16_t;
typedef __attribute__((ext_vector_type(8))) short short8;
typedef __attribute__((ext_vector_type(4))) short short4v;
typedef __attribute__((ext_vector_type(4))) float f32x4;

struct __align__(8) EPair { int c; float v; };

#define DEG_MASK ((1ULL << 40) - 1ULL)
#define DEG_ONE  (1ULL << 40)
#define FXS 1048576.0f

__device__ __forceinline__ float bf2f(unsigned short u) {
    union { unsigned int i; float f; } v;
    v.i = ((unsigned int)u) << 16;
    return v.f;
}
__device__ __forceinline__ bf16_t f2bf(float f) {
    union { float f; unsigned int i; } v;
    v.f = f;
    unsigned int x = v.i;
    return (bf16_t)((x + 0x7fffu + ((x >> 16) & 1u)) >> 16);
}
// dual-dtype param read: flag=1 -> fp32 storage, flag=0 -> bf16 storage
__device__ __forceinline__ float ldp(const void* b, int i, int f) {
    return f ? ((const float*)b)[i] : bf2f(((const unsigned short*)b)[i]);
}

// ---------------- dtype detection ----------------
__global__ __launch_bounds__(64) void detect_kernel(const void* xraw, const void* rvraw,
                                                    int* __restrict__ flag) {
    int lane = threadIdx.x;
    const unsigned short* xs = (const unsigned short*)xraw;
    float v0 = bf2f(xs[lane * 2]);
    float v1 = bf2f(xs[lane * 2 + 1]);
    bool crazy = !(fabsf(v0) < 1e6f) || !(fabsf(v1) < 1e6f);
    unsigned long long m = __ballot(crazy);
    if (lane == 0) {
        unsigned int rw = ((const unsigned int*)rvraw)[0];
        int isf32 = (m != 0ull) || ((rw & 0xffffu) == 0u);
        *flag = isf32 ? 1 : 0;
    }
}

// ---------------- merged preprocessing ----------------
// A: canonicalize x -> bf16 (4-wide);  B: u64-packed dst histogram (count<<40 | deg_fx);
// C: graph histogram with wave-run aggregation (batch is sorted).
__global__ __launch_bounds__(256) void prep_kernel(const void* __restrict__ x, bf16_t* __restrict__ xc,
                                                   const void* __restrict__ ew,
                                                   const int* __restrict__ dst,
                                                   const int* __restrict__ batch,
                                                   unsigned long long* __restrict__ cd,
                                                   int* __restrict__ gcount,
                                                   const int* __restrict__ flag) {
    int i = blockIdx.x * blockDim.x + threadIdx.x;
    int stride = gridDim.x * blockDim.x;
    int f = *flag;
    if (f) {
        const float4* xs = (const float4*)x;
        for (int j = i; j < NN * DIN / 4; j += stride) {
            float4 w = xs[j];
            short4v o;
            o[0] = (short)f2bf(w.x); o[1] = (short)f2bf(w.y);
            o[2] = (short)f2bf(w.z); o[3] = (short)f2bf(w.w);
            *(short4v*)&xc[j * 4] = o;
        }
    } else {
        const uint2* xs = (const uint2*)x;
        for (int j = i; j < NN * DIN / 4; j += stride)
            *(uint2*)&xc[j * 4] = xs[j];
    }
    for (int j = i; j < NE; j += stride) {
        float w = ldp(ew, j, f);
        int d = dst[j];
        unsigned long long wfx = (unsigned long long)(unsigned int)(w * FXS + 0.5f);
        atomicAdd(&cd[d], DEG_ONE | wfx);
    }
    int lane = threadIdx.x & 63;
    for (int j = i; j < NN; j += stride) {
        int b = batch[j];
        bool boundary = (lane == 0) || (j == 0) || (batch[j - 1] != b);
        unsigned long long bmask = __ballot(boundary);
        bool islast = (lane == 63) || (j + 1 >= NN) || (batch[j + 1] != b);
        if (islast) {
            unsigned long long below = bmask & ((lane == 63) ? ~0ull : ((1ull << (lane + 1)) - 1ull));
            int first = 63 - __builtin_clzll(below);
            atomicAdd(&gcount[b], lane - first + 1);
        }
    }
}

// ---------------- scan counts -> rowptr, compute dinv (single block, shfl scan) ----------------
__global__ __launch_bounds__(1024) void scan_rowptr(const unsigned long long* __restrict__ cd,
                                                    int* __restrict__ rowptr,
                                                    float* __restrict__ dinv) {
    __shared__ int wsum[16];
    __shared__ int s_tot;
    __shared__ int s_run;
    int tid = threadIdx.x, lane = tid & 63, wid = tid >> 6;
    if (tid == 0) s_run = 0;
    __syncthreads();
    for (int base = 0; base < NN; base += 8192) {
        int i0 = base + tid * 8;
        int v[8];
        int tsum = 0;
#pragma unroll
        for (int k = 0; k < 8; k++) {
            int idx = i0 + k;
            if (idx < NN) {
                unsigned long long cv = cd[idx];
                v[k] = (int)(cv >> 40);
                float deg = (float)(cv & DEG_MASK) * (1.0f / FXS);
                dinv[idx] = rsqrtf(deg + 1.0f);
            } else v[k] = 0;
            tsum += v[k];
        }
        int sc = tsum;
#pragma unroll
        for (int off = 1; off < 64; off <<= 1) {
            int t = __shfl_up(sc, off, 64);
            if (lane >= off) sc += t;
        }
        if (lane == 63) wsum[wid] = sc;
        __syncthreads();
        if (wid == 0 && lane < 16) {
            int ws = wsum[lane];
            int scw = ws;
#pragma unroll
            for (int off = 1; off < 16; off <<= 1) {
                int t = __shfl_up(scw, off, 64);
                if (lane >= off) scw += t;
            }
            if (lane == 15) s_tot = scw;
            wsum[lane] = scw - ws;
        }
        __syncthreads();
        int excl = s_run + wsum[wid] + (sc - tsum);
#pragma unroll
        for (int k = 0; k < 8; k++) {
            if (i0 + k < NN) rowptr[i0 + k] = excl;
            excl += v[k];
        }
        __syncthreads();
        if (tid == 0) s_run += s_tot;
    }
    if (tid == 0) rowptr[NN] = s_run;
}

// ---------------- scatter edges into CSR (slot alloc via u64 count decrement) ----------------
__global__ __launch_bounds__(256) void scatter_kernel(const int* __restrict__ src,
                                                      const int* __restrict__ dst,
                                                      const void* __restrict__ ew,
                                                      const float* __restrict__ dinv,
                                                      const int* __restrict__ rowptr,
                                                      unsigned long long* __restrict__ cd,
                                                      EPair* __restrict__ ep,
                                                      const int* __restrict__ flag) {
    int i = blockIdx.x * blockDim.x + threadIdx.x;
    int f = *flag;
    if (i < NE) {
        int s = src[i], d = dst[i];
        float nv = dinv[s] * ldp(ew, i, f) * dinv[d];
        unsigned long long old = atomicAdd(&cd[d], (unsigned long long)0 - DEG_ONE);
        int pos = rowptr[d] + (int)(old >> 40) - 1;
        EPair pr;
        pr.c = s;
        pr.v = nv;
        ep[pos] = pr;
    }
}

// ---------------- W pre-pack into MFMA B-fragment order ----------------
__device__ __forceinline__ void pack_one(const void* __restrict__ W, bf16_t* __restrict__ P,
                                         int S, int idx, int f) {
    int lane = idx & 63;
    int ts = idx >> 6;
    int s = ts % S;
    int t = ts / S;
    int q = lane >> 4, m = lane & 15;
    int colbase = t * 16 + m;
    int krow = 32 * s + 8 * q;
#pragma unroll
    for (int j = 0; j < 8; j++) P[idx * 8 + j] = f2bf(ldp(W, (krow + j) * 256 + colbase, f));
}

__global__ __launch_bounds__(256) void pack_both(const void* __restrict__ W1, bf16_t* __restrict__ P1,
                                                 const void* __restrict__ W2, bf16_t* __restrict__ P2,
                                                 const int* __restrict__ flag) {
    int idx = blockIdx.x * blockDim.x + threadIdx.x;
    int f = *flag;
    if (idx < 16 * 4 * 64) {
        pack_one(W1, P1, 4, idx, f);
    } else {
        idx -= 16 * 4 * 64;
        if (idx < 16 * 8 * 64) pack_one(W2, P2, 8, idx, f);
    }
}

// ---------------- fused layer: shfl-fed gather/aggregate -> MFMA -> BN/ReLU -> pool ----------------
template <int K, bool WRITE_OUT>
__global__ __launch_bounds__(256) void fused_layer(const bf16_t* __restrict__ X,
                                                   const bf16_t* __restrict__ P,
                                                   const int* __restrict__ rowptr,
                                                   const EPair* __restrict__ ep,
                                                   const float* __restrict__ dinv,
                                                   const int* __restrict__ batch,
                                                   const void* __restrict__ bias,
                                                   const void* __restrict__ gam,
                                                   const void* __restrict__ bet,
                                                   const void* __restrict__ rmean,
                                                   const void* __restrict__ rvar,
                                                   const int* __restrict__ flag,
                                                   bf16_t* __restrict__ outbuf,
                                                   float* __restrict__ embf) {
    constexpr int S = K / 32;
    constexpr int ROWELL = K + 8;
    constexpr int F = K / 64;   // 2 (K=128) or 4 (K=256) features/lane
    constexpr int UN = 8;       // X-row gathers in flight
    __shared__ __align__(16) bf16_t tile[4][16 * ROWELL];
    int fl = *flag;
    int widx = threadIdx.x >> 6;
    int lane = threadIdx.x & 63;
    int gwave = blockIdx.x * 4 + widx;
    bool active = (gwave * 16) < NN;
    int rowbase = active ? gwave * 16 : 0;
    bf16_t* T = tile[widx];
    int f0 = lane * F;

    // one coalesced load covers all 16 node ranges + dinv values
    int rp = rowptr[rowbase + (lane < 17 ? lane : 16)];
    float dvv = dinv[rowbase + (lane < 16 ? lane : 15)];

    // phase 1: per node, edge (c,v) pairs come from ONE coalesced ep block load + shfl;
    // X-row gathers are the only memory chain, issued UN at a time.
    EPair cur = ep[__shfl(rp, 0) + lane];
    for (int r = 0; r < 16; r++) {
        int e0 = __shfl(rp, r);
        int e1 = __shfl(rp, r + 1);
        int n = e1 - e0;
        float di = __shfl(dvv, r);
        float selfw = di * di;
        int node = rowbase + r;
        // prefetch next node's edge block (CSR-contiguous: starts at e1; ep is padded by 64)
        EPair nxt = ep[e1 + lane];
        float acc[F];
        if constexpr (K == 128) {
            uint32_t w = *(const uint32_t*)(X + (size_t)node * K + f0);
            acc[0] = bf2f((unsigned short)(w & 0xffffu)) * selfw;
            acc[1] = bf2f((unsigned short)(w >> 16)) * selfw;
        } else {
            uint2 w = *(const uint2*)(X + (size_t)node * K + f0);
            acc[0] = bf2f((unsigned short)(w.x & 0xffffu)) * selfw;
            acc[1] = bf2f((unsigned short)(w.x >> 16)) * selfw;
            acc[2] = bf2f((unsigned short)(w.y & 0xffffu)) * selfw;
            acc[3] = bf2f((unsigned short)(w.y >> 16)) * selfw;
        }
        int base = 0;
        while (base < n) {
            int blk = min(n - base, 64);
            for (int u0 = 0; u0 < blk; u0 += UN) {
                int cc[UN];
                float vv[UN];
#pragma unroll
                for (int u = 0; u < UN; u++) {
                    int idx = u0 + u;
                    bool ok = idx < blk;
                    int sl = ok ? idx : 0;
                    int c = __shfl(cur.c, sl);
                    float v = __shfl(cur.v, sl);
                    cc[u] = ok ? c : 0;
                    vv[u] = ok ? v : 0.f;
                }
                if constexpr (K == 128) {
                    uint32_t w[UN];
#pragma unroll
                    for (int u = 0; u < UN; u++) w[u] = *(const uint32_t*)(X + (size_t)cc[u] * K + f0);
#pragma unroll
                    for (int u = 0; u < UN; u++) {
                        acc[0] += bf2f((unsigned short)(w[u] & 0xffffu)) * vv[u];
                        acc[1] += bf2f((unsigned short)(w[u] >> 16)) * vv[u];
                    }
                } else {
                    uint2 w[UN];
#pragma unroll
                    for (int u = 0; u < UN; u++) w[u] = *(const uint2*)(X + (size_t)cc[u] * K + f0);
#pragma unroll
                    for (int u = 0; u < UN; u++) {
                        acc[0] += bf2f((unsigned short)(w[u].x & 0xffffu)) * vv[u];
                        acc[1] += bf2f((unsigned short)(w[u].x >> 16)) * vv[u];
                        acc[2] += bf2f((unsigned short)(w[u].y & 0xffffu)) * vv[u];
                        acc[3] += bf2f((unsigned short)(w[u].y >> 16)) * vv[u];
                    }
                }
            }
            base += 64;
            if (base < n) cur = ep[e0 + base + lane];
        }
        cur = nxt;
        if constexpr (K == 128) {
            uint32_t w = (uint32_t)f2bf(acc[0]) | ((uint32_t)f2bf(acc[1]) << 16);
            *(uint32_t*)&T[r * ROWELL + f0] = w;
        } else {
            short4v o;
#pragma unroll
            for (int j = 0; j < 4; j++) o[j] = (short)f2bf(acc[j]);
            *(short4v*)&T[r * ROWELL + f0] = o;
        }
    }
    __syncthreads();

    // phase 2: 16x16x32 bf16 MFMA over the LDS tile
    int m = lane & 15, q = lane >> 4;
    f32x4 acc16[16];
#pragma unroll
    for (int t = 0; t < 16; t++) acc16[t] = (f32x4){0.f, 0.f, 0.f, 0.f};
#pragma unroll
    for (int s = 0; s < S; s++) {
        short8 af = *(const short8*)&T[m * ROWELL + 32 * s + 8 * q];
#pragma unroll
        for (int t = 0; t < 16; t++) {
            short8 bfr = *(const short8*)(P + ((size_t)(t * S + s) * 64 + lane) * 8);
            acc16[t] = __builtin_amdgcn_mfma_f32_16x16x32_bf16(af, bfr, acc16[t], 0, 0, 0);
        }
    }

    // epilogue: bias+BN+ReLU, optional feature write, pooled atomics
    int g0 = batch[rowbase];
    int g15 = batch[rowbase + 15];
    bool uni = (g0 == g15);
#pragma unroll
    for (int t = 0; t < 16; t++) {
        int col = t * 16 + m;
        float a = rsqrtf(ldp(rvar, col, fl) + BN_EPS) * ldp(gam, col, fl);
        float bc = (ldp(bias, col, fl) - ldp(rmean, col, fl)) * a + ldp(bet, col, fl);
        float colsum = 0.f;
#pragma unroll
        for (int r = 0; r < 4; r++) {
            int row = q * 4 + r;
            float v = fmaxf(acc16[t][r] * a + bc, 0.f);
            if (WRITE_OUT && active) outbuf[(size_t)(rowbase + row) * 256 + col] = f2bf(v);
            if (uni) {
                colsum += v;
            } else if (active) {
                atomicAdd(&embf[(size_t)batch[rowbase + row] * 256 + col], v);
            }
        }
        if (uni) {
            colsum += __shfl_xor(colsum, 16, 64);
            colsum += __shfl_xor(colsum, 32, 64);
            if (q == 0 && active) atomicAdd(&embf[(size_t)g0 * 256 + col], colsum);
        }
    }
}

// ---------------- classifier MLP + emb finalize (one block per graph) ----------------
__global__ __launch_bounds__(256) void classifier_kernel(const float* __restrict__ embf,
                                                         const int* __restrict__ gcount,
                                                         const void* cW1, const void* cb1,
                                                         const void* cg1, const void* cbe1,
                                                         const void* crm1, const void* crv1,
                                                         const void* cW2, const void* cb2,
                                                         const void* cg2, const void* cbe2,
                                                         const void* crm2, const void* crv2,
                                                         const void* cW3, const void* cb3,
                                                         const int* __restrict__ flag,
                                                         void* __restrict__ d_out) {
    int b = blockIdx.x, tid = threadIdx.x;
    int fl = *flag;
    __shared__ float se[256];
    __shared__ float z1[256];
    __shared__ float z2[128];
    float cnt = (float)gcount[b];
    float mval = embf[b * 256 + tid] / fmaxf(cnt, 1.f);
    se[tid] = mval;
    if (fl) ((float*)d_out)[512 + b * 256 + tid] = mval;
    else    ((bf16_t*)d_out)[512 + b * 256 + tid] = f2bf(mval);
    __syncthreads();
    {
        float s = 0.f;
#pragma unroll 8
        for (int k = 0; k < 256; k++) s += se[k] * ldp(cW1, k * 256 + tid, fl);
        s += ldp(cb1, tid, fl);
        s = (s - ldp(crm1, tid, fl)) * rsqrtf(ldp(crv1, tid, fl) + BN_EPS) * ldp(cg1, tid, fl) + ldp(cbe1, tid, fl);
        z1[tid] = fmaxf(s, 0.f);
    }
    __syncthreads();
    if (tid < 128) {
        float s = 0.f;
#pragma unroll 8
        for (int k = 0; k < 256; k++) s += z1[k] * ldp(cW2, k * 128 + tid, fl);
        s += ldp(cb2, tid, fl);
        s = (s - ldp(crm2, tid, fl)) * rsqrtf(ldp(crv2, tid, fl) + BN_EPS) * ldp(cg2, tid, fl) + ldp(cbe2, tid, fl);
        z2[tid] = fmaxf(s, 0.f);
    }
    __syncthreads();
    if (tid < 2) {
        float s = 0.f;
        for (int k = 0; k < 128; k++) s += z2[k] * ldp(cW3, k * 2 + tid, fl);
        s += ldp(cb3, tid, fl);
        if (fl) ((float*)d_out)[b * 2 + tid] = s;
        else    ((bf16_t*)d_out)[b * 2 + tid] = f2bf(s);
    }
}

// ---------------- launch ----------------
extern "C" void kernel_launch(void* const* d_in, const int* in_sizes, int n_in,
                              void* d_out, int out_size, void* d_ws, size_t ws_size,
                              hipStream_t stream) {
    const void* x    = d_in[0];
    const int*  eidx = (const int*)d_in[1];
    const void* ew   = d_in[2];
    const int*  batch= (const int*)d_in[3];
    const void* W1   = d_in[4];
    const void* b1   = d_in[5];
    const void* g1   = d_in[6];
    const void* be1  = d_in[7];
    const void* rm1  = d_in[8];
    const void* rv1  = d_in[9];
    const void* W2   = d_in[10];
    const void* b2   = d_in[11];
    const void* g2   = d_in[12];
    const void* be2  = d_in[13];
    const void* rm2  = d_in[14];
    const void* rv2  = d_in[15];
    const void* cW1  = d_in[16];
    const void* cb1  = d_in[17];
    const void* cg1  = d_in[18];
    const void* cbe1 = d_in[19];
    const void* crm1 = d_in[20];
    const void* crv1 = d_in[21];
    const void* cW2  = d_in[22];
    const void* cb2  = d_in[23];
    const void* cg2  = d_in[24];
    const void* cbe2 = d_in[25];
    const void* crm2 = d_in[26];
    const void* crv2 = d_in[27];
    const void* cW3  = d_in[28];
    const void* cb3  = d_in[29];

    const int* src = eidx;
    const int* dst = eidx + NE;

    char* p = (char*)d_ws;
    auto alloc = [&](size_t bytes) -> void* {
        void* r = (void*)p;
        p += (bytes + 255) & ~(size_t)255;
        return r;
    };
    int*    dflag  = (int*)alloc(256);
    // --- contiguous zero-init region: cd, gcount, embf ---
    unsigned long long* cd = (unsigned long long*)alloc((size_t)NN * 8);
    int*    gcount = (int*)alloc((size_t)NB * 4);
    float*  embf   = (float*)alloc((size_t)NB * 256 * 4);
    size_t zspan = (char*)p - (char*)cd;
    // --- rest ---
    int*    rowptr = (int*)alloc((size_t)(NN + 1) * 4);
    float*  dinv   = (float*)alloc((size_t)NN * 4);
    EPair*  ep     = (EPair*)alloc((size_t)(NE + 64) * 8);  // +64: prefetch pad
    bf16_t* xc     = (bf16_t*)alloc((size_t)NN * DIN * 2);
    bf16_t* pW1    = (bf16_t*)alloc((size_t)DIN * 256 * 2);
    bf16_t* pW2    = (bf16_t*)alloc((size_t)256 * 256 * 2);
    bf16_t* hl1    = (bf16_t*)alloc((size_t)NN * 256 * 2);
    // total ~ 92 MB

    detect_kernel<<<1, 64, 0, stream>>>(x, rv1, dflag);
    hipMemsetAsync(cd, 0, zspan, stream);

    prep_kernel<<<2048, 256, 0, stream>>>(x, xc, ew, dst, batch, cd, gcount, dflag);
    scan_rowptr<<<1, 1024, 0, stream>>>(cd, rowptr, dinv);
    scatter_kernel<<<NE / 256, 256, 0, stream>>>(src, dst, ew, dinv, rowptr, cd, ep, dflag);
    pack_both<<<48, 256, 0, stream>>>(W1, pW1, W2, pW2, dflag);

    int nwaves = NN / 16;                    // 6250
    int blocks = (nwaves + 3) / 4;           // 1563
    fused_layer<128, true><<<blocks, 256, 0, stream>>>(xc, pW1, rowptr, ep, dinv, batch,
                                                       b1, g1, be1, rm1, rv1, dflag, hl1, embf);
    fused_layer<256, false><<<blocks, 256, 0, stream>>>(hl1, pW2, rowptr, ep, dinv, batch,
                                                        b2, g2, be2, rm2, rv2, dflag, nullptr, embf);

    classifier_kernel<<<NB, 256, 0, stream>>>(embf, gcount,
                                              cW1, cb1, cg1, cbe1, crm1, crv1,
                                              cW2, cb2, cg2, cbe2, crm2, crv2,
                                              cW3, cb3, dflag, d_out);
}

// Round 6
// 749.510 us; speedup vs baseline: 2.3736x; 1.2459x over previous
//
#include <hip/hip_runtime.h>
#include <stdint.h>

#define NN 100000     // nodes
#define NE 1600000    // edges
#define NB 256        // graphs
#define DIN 128
#define HH 256
#define BN_EPS 1e-5f

typedef unsigned short bf16_t;
typedef __attribute__((ext_vector_type(8))) short short8;
typedef __attribute__((ext_vector_type(4))) short short4v;
typedef __attribute__((ext_vector_type(4))) float f32x4;

struct __align__(8) EPair { int c; float v; };

#define DEG_MASK ((1ULL << 40) - 1ULL)
#define DEG_ONE  (1ULL << 40)
#define FXS 1048576.0f

__device__ __forceinline__ float bf2f(unsigned short u) {
    union { unsigned int i; float f; } v;
    v.i = ((unsigned int)u) << 16;
    return v.f;
}
__device__ __forceinline__ bf16_t f2bf(float f) {
    union { float f; unsigned int i; } v;
    v.f = f;
    unsigned int x = v.i;
    return (bf16_t)((x + 0x7fffu + ((x >> 16) & 1u)) >> 16);
}
// dual-dtype param read: flag=1 -> fp32 storage, flag=0 -> bf16 storage
__device__ __forceinline__ float ldp(const void* b, int i, int f) {
    return f ? ((const float*)b)[i] : bf2f(((const unsigned short*)b)[i]);
}

// ---------------- dtype detection ----------------
__global__ __launch_bounds__(64) void detect_kernel(const void* xraw, const void* rvraw,
                                                    int* __restrict__ flag) {
    int lane = threadIdx.x;
    const unsigned short* xs = (const unsigned short*)xraw;
    float v0 = bf2f(xs[lane * 2]);
    float v1 = bf2f(xs[lane * 2 + 1]);
    bool crazy = !(fabsf(v0) < 1e6f) || !(fabsf(v1) < 1e6f);
    unsigned long long m = __ballot(crazy);
    if (lane == 0) {
        unsigned int rw = ((const unsigned int*)rvraw)[0];
        int isf32 = (m != 0ull) || ((rw & 0xffffu) == 0u);
        *flag = isf32 ? 1 : 0;
    }
}

// ---------------- merged preprocessing ----------------
__global__ __launch_bounds__(256) void prep_kernel(const void* __restrict__ x, bf16_t* __restrict__ xc,
                                                   const void* __restrict__ ew,
                                                   const int* __restrict__ dst,
                                                   const int* __restrict__ batch,
                                                   unsigned long long* __restrict__ cd,
                                                   int* __restrict__ gcount,
                                                   const int* __restrict__ flag) {
    int i = blockIdx.x * blockDim.x + threadIdx.x;
    int stride = gridDim.x * blockDim.x;
    int f = *flag;
    if (f) {
        const float4* xs = (const float4*)x;
        for (int j = i; j < NN * DIN / 4; j += stride) {
            float4 w = xs[j];
            short4v o;
            o[0] = (short)f2bf(w.x); o[1] = (short)f2bf(w.y);
            o[2] = (short)f2bf(w.z); o[3] = (short)f2bf(w.w);
            *(short4v*)&xc[j * 4] = o;
        }
    } else {
        const uint2* xs = (const uint2*)x;
        for (int j = i; j < NN * DIN / 4; j += stride)
            *(uint2*)&xc[j * 4] = xs[j];
    }
    for (int j = i; j < NE; j += stride) {
        float w = ldp(ew, j, f);
        int d = dst[j];
        unsigned long long wfx = (unsigned long long)(unsigned int)(w * FXS + 0.5f);
        atomicAdd(&cd[d], DEG_ONE | wfx);
    }
    int lane = threadIdx.x & 63;
    for (int j = i; j < NN; j += stride) {
        int b = batch[j];
        bool boundary = (lane == 0) || (j == 0) || (batch[j - 1] != b);
        unsigned long long bmask = __ballot(boundary);
        bool islast = (lane == 63) || (j + 1 >= NN) || (batch[j + 1] != b);
        if (islast) {
            unsigned long long below = bmask & ((lane == 63) ? ~0ull : ((1ull << (lane + 1)) - 1ull));
            int first = 63 - __builtin_clzll(below);
            atomicAdd(&gcount[b], lane - first + 1);
        }
    }
}

// ---------------- parallel 3-phase scan: counts -> rowptr (+dinv) ----------------
#define SCAN_NB ((NN + 1023) / 1024)   // 98

__global__ __launch_bounds__(1024) void scanA(const unsigned long long* __restrict__ cd,
                                              int* __restrict__ rowptr,
                                              float* __restrict__ dinv,
                                              int* __restrict__ bsum) {
    __shared__ int wsum[16];
    int tid = threadIdx.x, lane = tid & 63, wid = tid >> 6;
    int i = blockIdx.x * 1024 + tid;
    int v = 0;
    if (i < NN) {
        unsigned long long cv = cd[i];
        v = (int)(cv >> 40);
        dinv[i] = rsqrtf((float)(cv & DEG_MASK) * (1.0f / FXS) + 1.0f);
    }
    int sc = v;
#pragma unroll
    for (int off = 1; off < 64; off <<= 1) {
        int t = __shfl_up(sc, off, 64);
        if (lane >= off) sc += t;
    }
    if (lane == 63) wsum[wid] = sc;
    __syncthreads();
    if (wid == 0 && lane < 16) {
        int ws = wsum[lane];
        int scw = ws;
#pragma unroll
        for (int off = 1; off < 16; off <<= 1) {
            int t = __shfl_up(scw, off, 64);
            if (lane >= off) scw += t;
        }
        if (lane == 15) bsum[blockIdx.x] = scw;   // block total
        wsum[lane] = scw - ws;                    // exclusive wave offset
    }
    __syncthreads();
    if (i < NN) rowptr[i] = wsum[wid] + sc - v;   // exclusive within block
}

__global__ __launch_bounds__(64) void scanB(int* __restrict__ bsum, int* __restrict__ rowptr) {
    int lane = threadIdx.x;
    int i0 = lane * 2;
    int v0 = (i0 < SCAN_NB) ? bsum[i0] : 0;
    int v1 = (i0 + 1 < SCAN_NB) ? bsum[i0 + 1] : 0;
    int tsum = v0 + v1;
    int sc = tsum;
#pragma unroll
    for (int off = 1; off < 64; off <<= 1) {
        int t = __shfl_up(sc, off, 64);
        if (lane >= off) sc += t;
    }
    int excl = sc - tsum;
    if (i0 < SCAN_NB) bsum[i0] = excl;
    if (i0 + 1 < SCAN_NB) bsum[i0 + 1] = excl + v0;
    if (lane == 63) rowptr[NN] = sc;   // grand total = NE
}

__global__ __launch_bounds__(1024) void scanC(int* __restrict__ rowptr, const int* __restrict__ bsum) {
    int i = blockIdx.x * 1024 + threadIdx.x;
    if (i < NN) rowptr[i] += bsum[blockIdx.x];
}

// ---------------- scatter edges into CSR (slot alloc via u64 count decrement) ----------------
__global__ __launch_bounds__(256) void scatter_kernel(const int* __restrict__ src,
                                                      const int* __restrict__ dst,
                                                      const void* __restrict__ ew,
                                                      const float* __restrict__ dinv,
                                                      const int* __restrict__ rowptr,
                                                      unsigned long long* __restrict__ cd,
                                                      EPair* __restrict__ ep,
                                                      const int* __restrict__ flag) {
    int i = blockIdx.x * blockDim.x + threadIdx.x;
    int f = *flag;
    if (i < NE) {
        int s = src[i], d = dst[i];
        float nv = dinv[s] * ldp(ew, i, f) * dinv[d];
        unsigned long long old = atomicAdd(&cd[d], (unsigned long long)0 - DEG_ONE);
        int pos = rowptr[d] + (int)(old >> 40) - 1;
        EPair pr;
        pr.c = s;
        pr.v = nv;
        ep[pos] = pr;
    }
}

// ---------------- W pre-pack into MFMA B-fragment order ----------------
__device__ __forceinline__ void pack_one(const void* __restrict__ W, bf16_t* __restrict__ P,
                                         int S, int idx, int f) {
    int lane = idx & 63;
    int ts = idx >> 6;
    int s = ts % S;
    int t = ts / S;
    int q = lane >> 4, m = lane & 15;
    int colbase = t * 16 + m;
    int krow = 32 * s + 8 * q;
#pragma unroll
    for (int j = 0; j < 8; j++) P[idx * 8 + j] = f2bf(ldp(W, (krow + j) * 256 + colbase, f));
}

__global__ __launch_bounds__(256) void pack_both(const void* __restrict__ W1, bf16_t* __restrict__ P1,
                                                 const void* __restrict__ W2, bf16_t* __restrict__ P2,
                                                 const int* __restrict__ flag) {
    int idx = blockIdx.x * blockDim.x + threadIdx.x;
    int f = *flag;
    if (idx < 16 * 4 * 64) {
        pack_one(W1, P1, 4, idx, f);
    } else {
        idx -= 16 * 4 * 64;
        if (idx < 16 * 8 * 64) pack_one(W2, P2, 8, idx, f);
    }
}

// ---------------- fused layer: pair-gather aggregate -> MFMA -> BN/ReLU -> pool ----------------
// Half-wave split: lanes 0-31 fetch even edges' rows, lanes 32-63 odd edges' rows.
// One load instruction covers 2 rows; UN=8 instructions -> 16 rows in flight/wave.
template <int K, bool WRITE_OUT>
__global__ __launch_bounds__(256, 4) void fused_layer(const bf16_t* __restrict__ X,
                                                      const bf16_t* __restrict__ P,
                                                      const int* __restrict__ rowptr,
                                                      const EPair* __restrict__ ep,
                                                      const float* __restrict__ dinv,
                                                      const int* __restrict__ batch,
                                                      const void* __restrict__ bias,
                                                      const void* __restrict__ gam,
                                                      const void* __restrict__ bet,
                                                      const void* __restrict__ rmean,
                                                      const void* __restrict__ rvar,
                                                      const int* __restrict__ flag,
                                                      bf16_t* __restrict__ outbuf,
                                                      float* __restrict__ embf) {
    constexpr int S = K / 32;
    constexpr int ROWELL = K + 8;
    constexpr int FPL = K / 32;   // features per half-lane: 4 (K=128) or 8 (K=256)
    constexpr int UN = 8;         // paired load instructions in flight (16 edges)
    __shared__ __align__(16) bf16_t tile[4][16 * ROWELL];
    int fl = *flag;
    int widx = threadIdx.x >> 6;
    int lane = threadIdx.x & 63;
    int h = lane >> 5;            // half index (which edge of the pair)
    int l5 = lane & 31;
    int f0 = l5 * FPL;
    int gwave = blockIdx.x * 4 + widx;
    bool active = (gwave * 16) < NN;
    int rowbase = active ? gwave * 16 : 0;
    bf16_t* T = tile[widx];

    int rp = rowptr[rowbase + (lane < 17 ? lane : 16)];
    float dvv = dinv[rowbase + (lane < 16 ? lane : 15)];

    EPair cur = ep[__shfl(rp, 0) + lane];
    for (int r = 0; r < 16; r++) {
        int e0 = __shfl(rp, r);
        int e1 = __shfl(rp, r + 1);
        int n = e1 - e0;
        float di = __shfl(dvv, r);
        int node = rowbase + r;
        EPair nxt = ep[e1 + lane];   // prefetch next node's edge window (ep padded)
        float acc[FPL];
        float sw = (h == 0) ? di * di : 0.f;   // self-loop term, counted once
        if constexpr (K == 128) {
            uint2 w0 = *(const uint2*)(X + (size_t)node * K + f0);
            acc[0] = bf2f((unsigned short)(w0.x & 0xffffu)) * sw;
            acc[1] = bf2f((unsigned short)(w0.x >> 16)) * sw;
            acc[2] = bf2f((unsigned short)(w0.y & 0xffffu)) * sw;
            acc[3] = bf2f((unsigned short)(w0.y >> 16)) * sw;
        } else {
            uint4 w0 = *(const uint4*)(X + (size_t)node * K + f0);
            acc[0] = bf2f((unsigned short)(w0.x & 0xffffu)) * sw;
            acc[1] = bf2f((unsigned short)(w0.x >> 16)) * sw;
            acc[2] = bf2f((unsigned short)(w0.y & 0xffffu)) * sw;
            acc[3] = bf2f((unsigned short)(w0.y >> 16)) * sw;
            acc[4] = bf2f((unsigned short)(w0.z & 0xffffu)) * sw;
            acc[5] = bf2f((unsigned short)(w0.z >> 16)) * sw;
            acc[6] = bf2f((unsigned short)(w0.w & 0xffffu)) * sw;
            acc[7] = bf2f((unsigned short)(w0.w >> 16)) * sw;
        }
        int base = 0;
        while (base < n) {
            int blk = min(n - base, 64);
            for (int u0 = 0; u0 < blk; u0 += 2 * UN) {
                int cc[UN];
                float vv[UN];
#pragma unroll
                for (int u = 0; u < UN; u++) {
                    int idx = u0 + 2 * u + h;
                    bool ok = idx < blk;
                    int sl = ok ? idx : 0;
                    int c = __shfl(cur.c, sl);
                    float v = __shfl(cur.v, sl);
                    cc[u] = ok ? c : node;   // clamped row is L1-hot (self row)
                    vv[u] = ok ? v : 0.f;
                }
                if constexpr (K == 128) {
                    uint2 w[UN];
#pragma unroll
                    for (int u = 0; u < UN; u++) w[u] = *(const uint2*)(X + (size_t)cc[u] * K + f0);
#pragma unroll
                    for (int u = 0; u < UN; u++) {
                        acc[0] += bf2f((unsigned short)(w[u].x & 0xffffu)) * vv[u];
                        acc[1] += bf2f((unsigned short)(w[u].x >> 16)) * vv[u];
                        acc[2] += bf2f((unsigned short)(w[u].y & 0xffffu)) * vv[u];
                        acc[3] += bf2f((unsigned short)(w[u].y >> 16)) * vv[u];
                    }
                } else {
                    uint4 w[UN];
#pragma unroll
                    for (int u = 0; u < UN; u++) w[u] = *(const uint4*)(X + (size_t)cc[u] * K + f0);
#pragma unroll
                    for (int u = 0; u < UN; u++) {
                        acc[0] += bf2f((unsigned short)(w[u].x & 0xffffu)) * vv[u];
                        acc[1] += bf2f((unsigned short)(w[u].x >> 16)) * vv[u];
                        acc[2] += bf2f((unsigned short)(w[u].y & 0xffffu)) * vv[u];
                        acc[3] += bf2f((unsigned short)(w[u].y >> 16)) * vv[u];
                        acc[4] += bf2f((unsigned short)(w[u].z & 0xffffu)) * vv[u];
                        acc[5] += bf2f((unsigned short)(w[u].z >> 16)) * vv[u];
                        acc[6] += bf2f((unsigned short)(w[u].w & 0xffffu)) * vv[u];
                        acc[7] += bf2f((unsigned short)(w[u].w >> 16)) * vv[u];
                    }
                }
            }
            base += 64;
            if (base < n) cur = ep[e0 + base + lane];
        }
        cur = nxt;
        // combine the two halves, then half 0 writes the tile row
#pragma unroll
        for (int j = 0; j < FPL; j++) acc[j] += __shfl_xor(acc[j], 32);
        if (h == 0) {
            if constexpr (K == 128) {
                short4v o;
#pragma unroll
                for (int j = 0; j < 4; j++) o[j] = (short)f2bf(acc[j]);
                *(short4v*)&T[r * ROWELL + f0] = o;
            } else {
                short8 o;
#pragma unroll
                for (int j = 0; j < 8; j++) o[j] = (short)f2bf(acc[j]);
                *(short8*)&T[r * ROWELL + f0] = o;
            }
        }
    }
    __syncthreads();

    // phase 2: 16x16x32 bf16 MFMA over the LDS tile
    int m = lane & 15, q = lane >> 4;
    f32x4 acc16[16];
#pragma unroll
    for (int t = 0; t < 16; t++) acc16[t] = (f32x4){0.f, 0.f, 0.f, 0.f};
#pragma unroll
    for (int s = 0; s < S; s++) {
        short8 af = *(const short8*)&T[m * ROWELL + 32 * s + 8 * q];
#pragma unroll
        for (int t = 0; t < 16; t++) {
            short8 bfr = *(const short8*)(P + ((size_t)(t * S + s) * 64 + lane) * 8);
            acc16[t] = __builtin_amdgcn_mfma_f32_16x16x32_bf16(af, bfr, acc16[t], 0, 0, 0);
        }
    }

    // epilogue: bias+BN+ReLU, optional feature write, pooled atomics
    int g0 = batch[rowbase];
    int g15 = batch[rowbase + 15];
    bool uni = (g0 == g15);
#pragma unroll
    for (int t = 0; t < 16; t++) {
        int col = t * 16 + m;
        float a = rsqrtf(ldp(rvar, col, fl) + BN_EPS) * ldp(gam, col, fl);
        float bc = (ldp(bias, col, fl) - ldp(rmean, col, fl)) * a + ldp(bet, col, fl);
        float colsum = 0.f;
#pragma unroll
        for (int r = 0; r < 4; r++) {
            int row = q * 4 + r;
            float v = fmaxf(acc16[t][r] * a + bc, 0.f);
            if (WRITE_OUT && active) outbuf[(size_t)(rowbase + row) * 256 + col] = f2bf(v);
            if (uni) {
                colsum += v;
            } else if (active) {
                atomicAdd(&embf[(size_t)batch[rowbase + row] * 256 + col], v);
            }
        }
        if (uni) {
            colsum += __shfl_xor(colsum, 16, 64);
            colsum += __shfl_xor(colsum, 32, 64);
            if (q == 0 && active) atomicAdd(&embf[(size_t)g0 * 256 + col], colsum);
        }
    }
}

// ---------------- classifier MLP + emb finalize (one block per graph) ----------------
__global__ __launch_bounds__(256) void classifier_kernel(const float* __restrict__ embf,
                                                         const int* __restrict__ gcount,
                                                         const void* cW1, const void* cb1,
                                                         const void* cg1, const void* cbe1,
                                                         const void* crm1, const void* crv1,
                                                         const void* cW2, const void* cb2,
                                                         const void* cg2, const void* cbe2,
                                                         const void* crm2, const void* crv2,
                                                         const void* cW3, const void* cb3,
                                                         const int* __restrict__ flag,
                                                         void* __restrict__ d_out) {
    int b = blockIdx.x, tid = threadIdx.x;
    int fl = *flag;
    __shared__ float se[256];
    __shared__ float z1[256];
    __shared__ float z2[128];
    float cnt = (float)gcount[b];
    float mval = embf[b * 256 + tid] / fmaxf(cnt, 1.f);
    se[tid] = mval;
    if (fl) ((float*)d_out)[512 + b * 256 + tid] = mval;
    else    ((bf16_t*)d_out)[512 + b * 256 + tid] = f2bf(mval);
    __syncthreads();
    {
        float s = 0.f;
#pragma unroll 8
        for (int k = 0; k < 256; k++) s += se[k] * ldp(cW1, k * 256 + tid, fl);
        s += ldp(cb1, tid, fl);
        s = (s - ldp(crm1, tid, fl)) * rsqrtf(ldp(crv1, tid, fl) + BN_EPS) * ldp(cg1, tid, fl) + ldp(cbe1, tid, fl);
        z1[tid] = fmaxf(s, 0.f);
    }
    __syncthreads();
    if (tid < 128) {
        float s = 0.f;
#pragma unroll 8
        for (int k = 0; k < 256; k++) s += z1[k] * ldp(cW2, k * 128 + tid, fl);
        s += ldp(cb2, tid, fl);
        s = (s - ldp(crm2, tid, fl)) * rsqrtf(ldp(crv2, tid, fl) + BN_EPS) * ldp(cg2, tid, fl) + ldp(cbe2, tid, fl);
        z2[tid] = fmaxf(s, 0.f);
    }
    __syncthreads();
    if (tid < 2) {
        float s = 0.f;
        for (int k = 0; k < 128; k++) s += z2[k] * ldp(cW3, k * 2 + tid, fl);
        s += ldp(cb3, tid, fl);
        if (fl) ((float*)d_out)[b * 2 + tid] = s;
        else    ((bf16_t*)d_out)[b * 2 + tid] = f2bf(s);
    }
}

// ---------------- launch ----------------
extern "C" void kernel_launch(void* const* d_in, const int* in_sizes, int n_in,
                              void* d_out, int out_size, void* d_ws, size_t ws_size,
                              hipStream_t stream) {
    const void* x    = d_in[0];
    const int*  eidx = (const int*)d_in[1];
    const void* ew   = d_in[2];
    const int*  batch= (const int*)d_in[3];
    const void* W1   = d_in[4];
    const void* b1   = d_in[5];
    const void* g1   = d_in[6];
    const void* be1  = d_in[7];
    const void* rm1  = d_in[8];
    const void* rv1  = d_in[9];
    const void* W2   = d_in[10];
    const void* b2   = d_in[11];
    const void* g2   = d_in[12];
    const void* be2  = d_in[13];
    const void* rm2  = d_in[14];
    const void* rv2  = d_in[15];
    const void* cW1  = d_in[16];
    const void* cb1  = d_in[17];
    const void* cg1  = d_in[18];
    const void* cbe1 = d_in[19];
    const void* crm1 = d_in[20];
    const void* crv1 = d_in[21];
    const void* cW2  = d_in[22];
    const void* cb2  = d_in[23];
    const void* cg2  = d_in[24];
    const void* cbe2 = d_in[25];
    const void* crm2 = d_in[26];
    const void* crv2 = d_in[27];
    const void* cW3  = d_in[28];
    const void* cb3  = d_in[29];

    const int* src = eidx;
    const int* dst = eidx + NE;

    char* p = (char*)d_ws;
    auto alloc = [&](size_t bytes) -> void* {
        void* r = (void*)p;
        p += (bytes + 255) & ~(size_t)255;
        return r;
    };
    int*    dflag  = (int*)alloc(256);
    // --- contiguous zero-init region: cd, gcount, embf ---
    unsigned long long* cd = (unsigned long long*)alloc((size_t)NN * 8);
    int*    gcount = (int*)alloc((size_t)NB * 4);
    float*  embf   = (float*)alloc((size_t)NB * 256 * 4);
    size_t zspan = (char*)p - (char*)cd;
    // --- rest ---
    int*    rowptr = (int*)alloc((size_t)(NN + 1) * 4);
    float*  dinv   = (float*)alloc((size_t)NN * 4);
    int*    bsum   = (int*)alloc((size_t)SCAN_NB * 4);
    EPair*  ep     = (EPair*)alloc((size_t)(NE + 64) * 8);  // +64: prefetch pad
    bf16_t* xc     = (bf16_t*)alloc((size_t)NN * DIN * 2);
    bf16_t* pW1    = (bf16_t*)alloc((size_t)DIN * 256 * 2);
    bf16_t* pW2    = (bf16_t*)alloc((size_t)256 * 256 * 2);
    bf16_t* hl1    = (bf16_t*)alloc((size_t)NN * 256 * 2);
    // total ~ 92 MB

    detect_kernel<<<1, 64, 0, stream>>>(x, rv1, dflag);
    hipMemsetAsync(cd, 0, zspan, stream);

    prep_kernel<<<2048, 256, 0, stream>>>(x, xc, ew, dst, batch, cd, gcount, dflag);
    scanA<<<SCAN_NB, 1024, 0, stream>>>(cd, rowptr, dinv, bsum);
    scanB<<<1, 64, 0, stream>>>(bsum, rowptr);
    scanC<<<SCAN_NB, 1024, 0, stream>>>(rowptr, bsum);
    scatter_kernel<<<NE / 256, 256, 0, stream>>>(src, dst, ew, dinv, rowptr, cd, ep, dflag);
    pack_both<<<48, 256, 0, stream>>>(W1, pW1, W2, pW2, dflag);

    int nwaves = NN / 16;                    // 6250
    int blocks = (nwaves + 3) / 4;           // 1563
    fused_layer<128, true><<<blocks, 256, 0, stream>>>(xc, pW1, rowptr, ep, dinv, batch,
                                                       b1, g1, be1, rm1, rv1, dflag, hl1, embf);
    fused_layer<256, false><<<blocks, 256, 0, stream>>>(hl1, pW2, rowptr, ep, dinv, batch,
                                                        b2, g2, be2, rm2, rv2, dflag, nullptr, embf);

    classifier_kernel<<<NB, 256, 0, stream>>>(embf, gcount,
                                              cW1, cb1, cg1, cbe1, crm1, crv1,
                                              cW2, cb2, cg2, cbe2, crm2, crv2,
                                              cW3, cb3, dflag, d_out);
}